// Round 1
// baseline (189.782 us; speedup 1.0000x reference)
//
#include <hip/hip_runtime.h>

#define NSITES 262144

// ws layout: G  [NSITES][32] floats at offset 0        (32 MiB)
//            Sp [NSITES][32] floats at offset 32 MiB   (32 MiB)
// j = b*8 + o (site-major packing so a neighbor gather reads 128 contiguous bytes)

__global__ __launch_bounds__(256) void prep_kernel(
    const float* __restrict__ In,       // [4][8][NSITES]
    const float* __restrict__ Weights,  // [8][8][16]
    const float* __restrict__ bias,     // [8][8]
    float* __restrict__ G,
    float* __restrict__ Sp)
{
    __shared__ float ws[8][8], wn[8][8], be[8];
    int t = threadIdx.x;
    if (t < 64) {
        int o = t >> 3, k = t & 7;
        float s0 = 0.f, s1 = 0.f;
        #pragma unroll
        for (int s = 0; s < 8; ++s) {
            s0 += Weights[s*128 + o*16 + k];
            s1 += Weights[s*128 + o*16 + 8 + k];
        }
        ws[o][k] = s0; wn[o][k] = s1;
    } else if (t < 72) {
        int o = t - 64;
        float s = 0.f;
        #pragma unroll
        for (int q = 0; q < 8; ++q) s += bias[q*8 + o];
        be[o] = s;
    }
    __syncthreads();

    int site = blockIdx.x * 256 + t;
    float x[4][8];
    #pragma unroll
    for (int b = 0; b < 4; ++b)
        #pragma unroll
        for (int i = 0; i < 8; ++i)
            x[b][i] = In[(b*8 + i) * NSITES + site];   // coalesced: lane stride 4B

    float4* G4 = (float4*)(G  + (size_t)site * 32);
    float4* S4 = (float4*)(Sp + (size_t)site * 32);
    #pragma unroll
    for (int b = 0; b < 4; ++b) {
        float sv[8], gv[8];
        #pragma unroll
        for (int o = 0; o < 8; ++o) {
            float a0 = be[o], a1 = 0.f;
            #pragma unroll
            for (int i = 0; i < 8; ++i) {
                a0 = fmaf(ws[o][i], x[b][i], a0);
                a1 = fmaf(wn[o][i], x[b][i], a1);
            }
            sv[o] = a0; gv[o] = a1;
        }
        S4[b*2+0] = make_float4(sv[0], sv[1], sv[2], sv[3]);
        S4[b*2+1] = make_float4(sv[4], sv[5], sv[6], sv[7]);
        G4[b*2+0] = make_float4(gv[0], gv[1], gv[2], gv[3]);
        G4[b*2+1] = make_float4(gv[4], gv[5], gv[6], gv[7]);
    }
}

__global__ __launch_bounds__(256) void gather_kernel(
    const float* __restrict__ Sp,
    const float* __restrict__ G,
    const int*   __restrict__ NN,   // [13][NSITES], rows 1..12 used
    float*       __restrict__ out)  // [32][NSITES]
{
    __shared__ float lds[32][65];   // [j][local site], padded: conflict-free both phases
    int t  = threadIdx.x;           // 256
    int j  = t & 31;                // component b*8+o
    int s0 = t >> 5;                // 0..7
    int base = blockIdx.x * 64;     // 64 sites per block

    for (int r = 0; r < 8; ++r) {
        int ls = r*8 + s0;
        int n  = base + ls;
        float sp = Sp[(size_t)n * 32 + j];   // coalesced 256B per wave
        float acc = 0.f;
        #pragma unroll
        for (int z = 1; z < 13; ++z) {
            int m = NN[z * NSITES + n];          // same addr across 32 lanes -> broadcast
            float gv = G[(size_t)m * 32 + j];    // 128B fully-used gather per site
            float x = sp + gv;
            float e = __expf(-fabsf(x));
            acc += fmaxf(x, 0.f) + __logf(1.f + e);  // stable softplus
        }
        lds[j][ls] = acc;
    }
    __syncthreads();
    // coalesced channel-major writeback
    int ls = t & 63;
    int j0 = t >> 6;
    #pragma unroll
    for (int r = 0; r < 8; ++r) {
        int jj = j0 * 8 + r;
        out[(size_t)jj * NSITES + base + ls] = lds[jj][ls];
    }
}

extern "C" void kernel_launch(void* const* d_in, const int* in_sizes, int n_in,
                              void* d_out, int out_size, void* d_ws, size_t ws_size,
                              hipStream_t stream) {
    const float* In      = (const float*)d_in[0];
    const int*   NN      = (const int*)  d_in[1];
    const float* Weights = (const float*)d_in[2];
    const float* bias    = (const float*)d_in[3];
    float* out = (float*)d_out;

    float* G  = (float*)d_ws;                         // 32 MiB
    float* Sp = G + (size_t)NSITES * 32;              // 32 MiB

    prep_kernel<<<NSITES / 256, 256, 0, stream>>>(In, Weights, bias, G, Sp);
    gather_kernel<<<NSITES / 64, 256, 0, stream>>>(Sp, G, NN, out);
}

// Round 2
// 167.769 us; speedup vs baseline: 1.1312x; 1.1312x over previous
//
#include <hip/hip_runtime.h>

#define NSITES 262144

// ws layout: G  [NSITES][32] floats at offset 0        (32 MiB)
//            Sp [NSITES][32] floats at offset 32 MiB   (32 MiB)
// j = b*8 + o (site-major so a neighbor gather reads 128 contiguous bytes)

__global__ __launch_bounds__(256) void prep_kernel(
    const float* __restrict__ In,       // [4][8][NSITES]
    const float* __restrict__ Weights,  // [8][8][16]
    const float* __restrict__ bias,     // [8][8]
    float4* __restrict__ G4,
    float4* __restrict__ Sp4)
{
    __shared__ float ws[8][8], wn[8][8], be[8];
    __shared__ float st[256 * 33];      // [site][j], stride 33 -> 2-way banks (free)
    int t = threadIdx.x;
    if (t < 64) {
        int o = t >> 3, k = t & 7;
        float s0 = 0.f, s1 = 0.f;
        #pragma unroll
        for (int s = 0; s < 8; ++s) {
            s0 += Weights[s*128 + o*16 + k];
            s1 += Weights[s*128 + o*16 + 8 + k];
        }
        ws[o][k] = s0; wn[o][k] = s1;
    } else if (t < 72) {
        int o = t - 64;
        float s = 0.f;
        #pragma unroll
        for (int q = 0; q < 8; ++q) s += bias[q*8 + o];
        be[o] = s;
    }
    __syncthreads();

    int site = blockIdx.x * 256 + t;
    float x[4][8];
    #pragma unroll
    for (int b = 0; b < 4; ++b)
        #pragma unroll
        for (int i = 0; i < 8; ++i)
            x[b][i] = In[(b*8 + i) * NSITES + site];   // coalesced

    size_t blk4 = (size_t)blockIdx.x * 2048;           // float4 index of block's region
    float v[32];

    // ---- G pass ----
    #pragma unroll
    for (int b = 0; b < 4; ++b)
        #pragma unroll
        for (int o = 0; o < 8; ++o) {
            float a = 0.f;
            #pragma unroll
            for (int i = 0; i < 8; ++i) a = fmaf(wn[o][i], x[b][i], a);
            v[b*8 + o] = a;
        }
    #pragma unroll
    for (int j = 0; j < 32; ++j) st[t*33 + j] = v[j];
    __syncthreads();
    #pragma unroll
    for (int r = 0; r < 8; ++r) {
        int f = r*256 + t;                 // block-local float4 index
        int s = f >> 3, jj = (f & 7) << 2;
        G4[blk4 + f] = make_float4(st[s*33+jj], st[s*33+jj+1], st[s*33+jj+2], st[s*33+jj+3]);
    }
    __syncthreads();

    // ---- Sp pass (reuses LDS) ----
    #pragma unroll
    for (int b = 0; b < 4; ++b)
        #pragma unroll
        for (int o = 0; o < 8; ++o) {
            float a = be[o];
            #pragma unroll
            for (int i = 0; i < 8; ++i) a = fmaf(ws[o][i], x[b][i], a);
            v[b*8 + o] = a;
        }
    #pragma unroll
    for (int j = 0; j < 32; ++j) st[t*33 + j] = v[j];
    __syncthreads();
    #pragma unroll
    for (int r = 0; r < 8; ++r) {
        int f = r*256 + t;
        int s = f >> 3, jj = (f & 7) << 2;
        Sp4[blk4 + f] = make_float4(st[s*33+jj], st[s*33+jj+1], st[s*33+jj+2], st[s*33+jj+3]);
    }
}

// 8 lanes per site; each lane owns one float4 quad (j = 4q..4q+3).
// Amortizes NN load + gather addressing over 4 values.
__global__ __launch_bounds__(256) void gather_kernel(
    const float4* __restrict__ Sp4,
    const float4* __restrict__ G4,
    const int*    __restrict__ NN,   // [13][NSITES], rows 1..12 used
    float*        __restrict__ out)  // [32][NSITES]
{
    __shared__ float lds[32][33];
    int t    = threadIdx.x;          // 256
    int q    = t & 7;                // quad index
    int sl   = t >> 3;               // local site 0..31
    int base = blockIdx.x * 32;
    int n    = base + sl;

    float4 sp = Sp4[n*8 + q];
    float ax = 0.f, ay = 0.f, az = 0.f, aw = 0.f;

    #pragma unroll
    for (int z = 1; z < 13; ++z) {
        int m = NN[z * NSITES + n];       // 8 distinct addrs/wave (broadcast in 8-lane groups)
        float4 g = G4[m*8 + q];           // 128B fully-used line per site
        float x0 = sp.x + g.x;
        float x1 = sp.y + g.y;
        float x2 = sp.z + g.z;
        float x3 = sp.w + g.w;
        ax += fmaxf(x0, 0.f) + __logf(1.f + __expf(-fabsf(x0)));
        ay += fmaxf(x1, 0.f) + __logf(1.f + __expf(-fabsf(x1)));
        az += fmaxf(x2, 0.f) + __logf(1.f + __expf(-fabsf(x2)));
        aw += fmaxf(x3, 0.f) + __logf(1.f + __expf(-fabsf(x3)));
    }

    lds[4*q + 0][sl] = ax;
    lds[4*q + 1][sl] = ay;
    lds[4*q + 2][sl] = az;
    lds[4*q + 3][sl] = aw;
    __syncthreads();

    // coalesced channel-major writeback: 1024 floats, 4 per thread
    int s = t & 31;
    int j0 = t >> 5;
    #pragma unroll
    for (int r = 0; r < 4; ++r) {
        int j = r*8 + j0;
        out[j * NSITES + base + s] = lds[j][s];
    }
}

extern "C" void kernel_launch(void* const* d_in, const int* in_sizes, int n_in,
                              void* d_out, int out_size, void* d_ws, size_t ws_size,
                              hipStream_t stream) {
    const float* In      = (const float*)d_in[0];
    const int*   NN      = (const int*)  d_in[1];
    const float* Weights = (const float*)d_in[2];
    const float* bias    = (const float*)d_in[3];
    float* out = (float*)d_out;

    float4* G4  = (float4*)d_ws;                            // 32 MiB
    float4* Sp4 = G4 + (size_t)NSITES * 8;                  // 32 MiB

    prep_kernel<<<NSITES / 256, 256, 0, stream>>>(In, Weights, bias, G4, Sp4);
    gather_kernel<<<NSITES / 32, 256, 0, stream>>>(Sp4, G4, NN, out);
}

// Round 4
// 155.168 us; speedup vs baseline: 1.2231x; 1.0812x over previous
//
#include <hip/hip_runtime.h>
#include <hip/hip_fp16.h>

#define NSITES 262144

struct alignas(16) H8 { __half2 h[4]; };   // 8 fp16 values = 16 B

__device__ inline __half2 habs2_(__half2 x) {
    unsigned int u;
    __builtin_memcpy(&u, &x, 4);
    u &= 0x7FFF7FFFu;
    __half2 r;
    __builtin_memcpy(&r, &u, 4);
    return r;
}

// G  [NSITES][32] fp16 at ws+0       (16 MiB)   j = b*8+o, site-major (64 B/site)
// Sp [NSITES][32] fp16 at ws+16MiB   (16 MiB)

__global__ __launch_bounds__(256) void prep_kernel(
    const float* __restrict__ In,       // [4][8][NSITES]
    const float* __restrict__ Weights,  // [8][8][16]
    const float* __restrict__ bias,     // [8][8]
    H8* __restrict__ G,                 // [NSITES][4]
    H8* __restrict__ Sp)                // [NSITES][4]
{
    __shared__ float ws[8][8], wn[8][8], be[8];
    int t = threadIdx.x;
    if (t < 64) {
        int o = t >> 3, k = t & 7;
        float s0 = 0.f, s1 = 0.f;
        #pragma unroll
        for (int s = 0; s < 8; ++s) {
            s0 += Weights[s*128 + o*16 + k];
            s1 += Weights[s*128 + o*16 + 8 + k];
        }
        ws[o][k] = s0; wn[o][k] = s1;
    } else if (t < 72) {
        int o = t - 64;
        float s = 0.f;
        #pragma unroll
        for (int q = 0; q < 8; ++q) s += bias[q*8 + o];
        be[o] = s;
    }
    __syncthreads();

    int site = blockIdx.x * 256 + t;
    float x[4][8];
    #pragma unroll
    for (int b = 0; b < 4; ++b)
        #pragma unroll
        for (int i = 0; i < 8; ++i)
            x[b][i] = In[(b*8 + i) * NSITES + site];   // coalesced

    #pragma unroll
    for (int b = 0; b < 4; ++b) {          // quad q == b (8 comps per quad)
        H8 gv, sv;
        #pragma unroll
        for (int p = 0; p < 4; ++p) {      // pairs of o
            float g0 = 0.f, g1 = 0.f, s0 = be[2*p], s1 = be[2*p+1];
            #pragma unroll
            for (int i = 0; i < 8; ++i) {
                g0 = fmaf(wn[2*p  ][i], x[b][i], g0);
                g1 = fmaf(wn[2*p+1][i], x[b][i], g1);
                s0 = fmaf(ws[2*p  ][i], x[b][i], s0);
                s1 = fmaf(ws[2*p+1][i], x[b][i], s1);
            }
            gv.h[p] = __floats2half2_rn(g0, g1);
            sv.h[p] = __floats2half2_rn(s0, s1);
        }
        G [site*4 + b] = gv;   // 16B/lane at 64B stride; L2 merges to full lines
        Sp[site*4 + b] = sv;
    }
}

// 4 lanes per site; lane owns 8 comps (one 16B H8). 64 sites / block.
__global__ __launch_bounds__(256) void gather_kernel(
    const H8*  __restrict__ Sp,
    const H8*  __restrict__ G,
    const int* __restrict__ NN,    // [13][NSITES], rows 1..12 used
    float*     __restrict__ out)   // [32][NSITES]
{
    __shared__ float lds[32][65];
    int t    = threadIdx.x;        // 256
    int q    = t & 3;              // which 8-comp chunk
    int sl   = t >> 2;             // local site 0..63
    int base = blockIdx.x * 64;
    int n    = base + sl;

    H8 sp = Sp[n*4 + q];
    const __half2 NLOG2E = __float2half2_rn(-1.44269504f);
    const __half2 HALF2  = __float2half2_rn(0.5f);
    const __half2 ZERO2  = __float2half2_rn(0.f);
    const __half2 ONE2   = __float2half2_rn(1.f);
    __half2 acc[4]  = {ZERO2, ZERO2, ZERO2, ZERO2};
    __half2 prod[4] = {ONE2, ONE2, ONE2, ONE2};

    #pragma unroll
    for (int z = 1; z < 13; ++z) {
        int m = NN[z * NSITES + n];
        H8 g = G[m*4 + q];               // 64B/site granule, fully used
        #pragma unroll
        for (int k = 0; k < 4; ++k) {
            __half2 x  = __hadd2(sp.h[k], g.h[k]);
            __half2 ax = habs2_(x);
            // relu(x) = 0.5*(x+|x|)  (exact: pow2 scale)
            acc[k]  = __hfma2(__hadd2(x, ax), HALF2, acc[k]);
            __half2 y = __hmul2(ax, NLOG2E);                 // -|x|·log2e
            prod[k] = __hfma2(prod[k], h2exp2(y), prod[k]);  // Π (1+2^y)
        }
    }

    #pragma unroll
    for (int k = 0; k < 4; ++k) {
        __half2 l2 = h2log2(prod[k]);    // Σ ln(1+e^-|x|) = ln2·log2(Π)
        float r0 = __low2float (acc[k]) + 0.69314718f * __low2float (l2);
        float r1 = __high2float(acc[k]) + 0.69314718f * __high2float(l2);
        lds[q*8 + 2*k    ][sl] = r0;
        lds[q*8 + 2*k + 1][sl] = r1;
    }
    __syncthreads();

    int s  = t & 63;
    int j0 = t >> 6;                     // 0..3
    #pragma unroll
    for (int r = 0; r < 8; ++r) {
        int j = j0*8 + r;
        out[j * NSITES + base + s] = lds[j][s];   // coalesced 256B/inst
    }
}

extern "C" void kernel_launch(void* const* d_in, const int* in_sizes, int n_in,
                              void* d_out, int out_size, void* d_ws, size_t ws_size,
                              hipStream_t stream) {
    const float* In      = (const float*)d_in[0];
    const int*   NN      = (const int*)  d_in[1];
    const float* Weights = (const float*)d_in[2];
    const float* bias    = (const float*)d_in[3];
    float* out = (float*)d_out;

    H8* G  = (H8*)d_ws;                        // 16 MiB
    H8* Sp = G + (size_t)NSITES * 4;           // 16 MiB

    prep_kernel<<<NSITES / 256, 256, 0, stream>>>(In, Weights, bias, G, Sp);
    gather_kernel<<<NSITES / 64, 256, 0, stream>>>(Sp, G, NN, out);
}